// Round 7
// baseline (144.675 us; speedup 1.0000x reference)
//
#include <hip/hip_runtime.h>
#include <hip/hip_bf16.h>
#include <stdint.h>

// ============================================================================
// Fused causal self-attention block: QKV projection + flash attention.
// bf16 MFMA. No-max softmax (scores bounded; log2e folded into Q scale).
// Swapped QK^T (S^T) + transposed PV (O^T). k_attn: 512-thr blocks (8 waves x
// 16 q-rows -> 128-row q-tile), kv-chunks balanced-partitioned into <=8-tile
// pieces (576 blocks), K double-buffered (one barrier/tile), V direct from
// L2-resident Vt. 2 blocks/CU x 8 waves = 16 waves/CU (VGPR-capped max).
// ============================================================================

typedef __bf16 bf16x8 __attribute__((ext_vector_type(8)));
typedef float  f32x4  __attribute__((ext_vector_type(4)));
typedef unsigned int u32x4 __attribute__((ext_vector_type(4)));
typedef unsigned int u32x2 __attribute__((ext_vector_type(2)));

using bf16 = __hip_bfloat16;

#define AS1 __attribute__((address_space(1)))
#define AS3 __attribute__((address_space(3)))

__device__ __forceinline__ void gl_lds16(const void* g, void* l) {
  __builtin_amdgcn_global_load_lds((AS1 uint32_t*)g, (AS3 uint32_t*)l, 16, 0, 0);
}

// ---------------------------------------------------------------------------
// 1) W [1024][128] fp32 -> Wt[z][128][1024] bf16 (transpose via LDS tile)
// ---------------------------------------------------------------------------
__global__ __launch_bounds__(256) void k_wt(const float* __restrict__ Wq,
                                            const float* __restrict__ Wk,
                                            const float* __restrict__ Wv,
                                            bf16* __restrict__ Wt) {
  __shared__ bf16 t[64][72];
  const float* W = blockIdx.z == 0 ? Wq : (blockIdx.z == 1 ? Wk : Wv);
  int k0 = blockIdx.x * 64, n0 = blockIdx.y * 64;
  int tid = threadIdx.x;
  int r = tid >> 4, c4 = (tid & 15) * 4;
#pragma unroll
  for (int s = 0; s < 4; ++s) {
    int rr = r + s * 16;
    float4 v = *(const float4*)(W + (size_t)(k0 + rr) * 128 + n0 + c4);
    t[rr][c4 + 0] = __float2bfloat16(v.x);
    t[rr][c4 + 1] = __float2bfloat16(v.y);
    t[rr][c4 + 2] = __float2bfloat16(v.z);
    t[rr][c4 + 3] = __float2bfloat16(v.w);
  }
  __syncthreads();
  bf16* out = Wt + (size_t)blockIdx.z * 128 * 1024;
#pragma unroll
  for (int s = 0; s < 4; ++s) {
    int rn = r + s * 16;
    union { bf16 h[4]; u32x2 v; } u;
    u.h[0] = t[c4 + 0][rn]; u.h[1] = t[c4 + 1][rn];
    u.h[2] = t[c4 + 2][rn]; u.h[3] = t[c4 + 3][rn];
    *(u32x2*)(out + (size_t)(n0 + rn) * 1024 + k0 + c4) = u.v;
  }
}

// ---------------------------------------------------------------------------
// 2) fused QKV projection + in-kernel V transpose (unchanged, proven)
// ---------------------------------------------------------------------------
__global__ __launch_bounds__(512) void k_qkv(const float* __restrict__ X,
                                             const bf16* __restrict__ Wt,
                                             const float* __restrict__ bq,
                                             const float* __restrict__ bk,
                                             const float* __restrict__ bv,
                                             bf16* __restrict__ Qo,
                                             bf16* __restrict__ Ko,
                                             bf16* __restrict__ Vt) {
  __shared__ __align__(16) char smem[65536];
  float* Xs = (float*)smem;                  // [2][64*32] f32, 16 KB
  bf16* Ws = (bf16*)(smem + 16384);          // [2][3*128*32] bf16, 48 KB
  bf16* Vs = (bf16*)smem;                    // epilogue: [64][136], 17.4 KB

  const int m0 = blockIdx.x * 64;
  const int tid = threadIdx.x;
  const int lane = tid & 63;
  const int li = lane & 15, g = lane >> 4;
  const int wid = tid >> 6;
  const int wm = wid >> 2, wn = wid & 3;

  const int xr = tid >> 3;
  const int xc32 = (tid & 7) >> 1;
  const int xhf = tid & 1;
  const int wr = tid >> 2;
  const int wc = tid & 3;

  f32x4 acc[3][2][2] = {};

  {
    gl_lds16(X + (size_t)(m0 + xr) * 1024 + (xc32 ^ (xr & 3)) * 8 + xhf * 4,
             Xs + tid * 4);
#pragma unroll
    for (int z = 0; z < 3; ++z)
      gl_lds16(Wt + (size_t)z * 131072 + (size_t)wr * 1024 + (wc ^ (wr & 3)) * 8,
               Ws + z * 4096 + tid * 8);
  }
  int cur = 0;
  for (int kt = 0; kt < 32; ++kt) {
    __syncthreads();
    if (kt < 31) {
      const int k0 = (kt + 1) * 32;
      gl_lds16(X + (size_t)(m0 + xr) * 1024 + k0 + (xc32 ^ (xr & 3)) * 8 + xhf * 4,
               Xs + (cur ^ 1) * 2048 + tid * 4);
#pragma unroll
      for (int z = 0; z < 3; ++z)
        gl_lds16(Wt + (size_t)z * 131072 + (size_t)wr * 1024 + k0 + (wc ^ (wr & 3)) * 8,
                 Ws + (cur ^ 1) * 12288 + z * 4096 + tid * 8);
    }
    bf16x8 af[2];
#pragma unroll
    for (int mf = 0; mf < 2; ++mf) {
      int r = wm * 32 + mf * 16 + li;
      const float* xp = Xs + cur * 2048 + r * 32 + ((g ^ (r & 3)) * 8);
      f32x4 x0 = *(const f32x4*)xp;
      f32x4 x1 = *(const f32x4*)(xp + 4);
      union { bf16 h[8]; bf16x8 v; } u;
      u.h[0] = __float2bfloat16(x0[0]); u.h[1] = __float2bfloat16(x0[1]);
      u.h[2] = __float2bfloat16(x0[2]); u.h[3] = __float2bfloat16(x0[3]);
      u.h[4] = __float2bfloat16(x1[0]); u.h[5] = __float2bfloat16(x1[1]);
      u.h[6] = __float2bfloat16(x1[2]); u.h[7] = __float2bfloat16(x1[3]);
      af[mf] = u.v;
    }
#pragma unroll
    for (int z = 0; z < 3; ++z) {
#pragma unroll
      for (int nf = 0; nf < 2; ++nf) {
        int r = wn * 32 + nf * 16 + li;
        bf16x8 bfrag =
            *(const bf16x8*)(Ws + cur * 12288 + z * 4096 + r * 32 + ((g ^ (r & 3)) * 8));
#pragma unroll
        for (int mf = 0; mf < 2; ++mf)
          acc[z][mf][nf] = __builtin_amdgcn_mfma_f32_16x16x32_bf16(
              af[mf], bfrag, acc[z][mf][nf], 0, 0, 0);
      }
    }
    cur ^= 1;
  }

#pragma unroll
  for (int z = 0; z < 2; ++z) {
    const float* bias = z == 0 ? bq : bk;
    bf16* Out = z == 0 ? Qo : Ko;
    const float scale = z == 0 ? 0.12752404368678202f : 1.0f;
#pragma unroll
    for (int nf = 0; nf < 2; ++nf) {
      int col = wn * 32 + nf * 16 + li;
      float bb = bias[col];
#pragma unroll
      for (int mf = 0; mf < 2; ++mf)
#pragma unroll
        for (int j = 0; j < 4; ++j) {
          int row = m0 + wm * 32 + mf * 16 + g * 4 + j;
          Out[(size_t)row * 128 + col] =
              __float2bfloat16((acc[z][mf][nf][j] + bb) * scale);
        }
    }
  }

  __syncthreads();
#pragma unroll
  for (int nf = 0; nf < 2; ++nf) {
    int col = wn * 32 + nf * 16 + li;
    float bb = bv[col];
#pragma unroll
    for (int mf = 0; mf < 2; ++mf)
#pragma unroll
      for (int j = 0; j < 4; ++j) {
        int row = wm * 32 + mf * 16 + g * 4 + j;
        Vs[row * 136 + col] = __float2bfloat16(acc[2][mf][nf][j] + bb);
      }
  }
  __syncthreads();
  const int b = m0 >> 12;
  const int s_off = m0 & 4095;
#pragma unroll
  for (int t2 = 0; t2 < 2; ++t2) {
    int idx = tid + 512 * t2;
    int dv = idx & 127;
    int sg = idx >> 7;
    union { bf16 h[8]; u32x4 v; } u;
#pragma unroll
    for (int si = 0; si < 8; ++si) u.h[si] = Vs[(sg * 8 + si) * 136 + dv];
    *(u32x4*)(Vt + (size_t)(b * 128 + dv) * 4096 + s_off + sg * 8) = u.v;
  }
}

// ---------------------------------------------------------------------------
// 3) causal flash attention. 512 thr = 8 waves x 16 q-rows -> q-tile 128.
//    kv tiles for q-tile qt: n = 2(qt+1); chunks = a+1 (a = qt>>2), balanced
//    partition (lengths in [4,8]). blocks/batch = sum = 144 -> grid 576.
//    base(qt) = (a+1)(2a+r), r = qt&3. 2 blocks/CU x 8 waves = 16 waves/CU.
// ---------------------------------------------------------------------------
__global__ __launch_bounds__(512) void k_attn(const bf16* __restrict__ Qb,
                                              const bf16* __restrict__ Kb,
                                              const bf16* __restrict__ Vt,
                                              bf16* __restrict__ o_part,
                                              float* __restrict__ l_part) {
  __shared__ __align__(16) bf16 Kls[2][64 * 128];  // 32 KB, swizzled chunks
  __shared__ __align__(16) bf16 Pls[8][16 * 72];   // per-wave P[q][kv], 18 KB

  const int bid = blockIdx.x;
  const int slot = (bid & 7) * 72 + (bid >> 3);  // XCD swizzle, bijective
  const int b = slot / 144;
  const int s = slot - b * 144;
  int a = 0;
#pragma unroll
  for (int aa = 1; aa < 8; ++aa)
    if (2 * aa * (aa + 1) <= s) a = aa;
  const int t = s - 2 * a * (a + 1);
  const int tq = t / (a + 1);
  const int qt = 4 * a + tq;
  const int chunk = t - tq * (a + 1);
  const int ntiles = 2 * (qt + 1);
  const int nchunks = a + 1;
  const int clen = ntiles / nchunks;
  const int crem = ntiles - clen * nchunks;
  const int kt0 = chunk * clen + min(chunk, crem);
  const int kt1 = kt0 + clen + (chunk < crem ? 1 : 0) - 1;

  const int tid = threadIdx.x;
  const int lane = tid & 63;
  const int li = lane & 15, g = lane >> 4;
  const int w = tid >> 6;

  // Q fragments (B-operand of swapped QK^T): lane holds Q[qrow][...]
  const int qrow = qt * 128 + w * 16 + li;  // within batch
  bf16x8 qf[4];
#pragma unroll
  for (int ks = 0; ks < 4; ++ks)
    qf[ks] = *(const bf16x8*)(Qb +
        (size_t)(b * 4096 + qrow) * 128 + ks * 32 + g * 8);

  f32x4 o[8] = {};
  f32x4 lacc = {};
  bf16x8 ones;
#pragma unroll
  for (int e = 0; e < 8; ++e) ones[e] = (__bf16)1.0f;

  bf16* P = &Pls[w][0];
  const bf16* Vtb = Vt + (size_t)b * 128 * 4096;

  // prologue: stage K tile kt0 -> buf 0 (512 thr x 2 x 16B = 16 KB)
#pragma unroll
  for (int ii = 0; ii < 2; ++ii) {
    int c = tid + 512 * ii;
    int r = c >> 4, cc = c & 15;
    gl_lds16(Kb + (size_t)(b * 4096 + kt0 * 64 + r) * 128 + (cc ^ (r & 7)) * 8,
             &Kls[0][c * 8]);
  }
  int cur = 0;
  for (int kt = kt0; kt <= kt1; ++kt) {
    __syncthreads();  // buf[cur] staged; all waves done reading buf[cur^1]
    if (kt < kt1) {
      const int kv0n = (kt + 1) * 64;
#pragma unroll
      for (int ii = 0; ii < 2; ++ii) {
        int c = tid + 512 * ii;
        int r = c >> 4, cc = c & 15;
        gl_lds16(Kb + (size_t)(b * 4096 + kv0n + r) * 128 + (cc ^ (r & 7)) * 8,
                 &Kls[cur ^ 1][c * 8]);
      }
    }
    const bf16* Kl = &Kls[cur][0];
    const int kv0 = kt * 64;

    // V prefetch, first half (kv 0..31): hides under QK^T
    bf16x8 vf0[8];
#pragma unroll
    for (int dvf = 0; dvf < 8; ++dvf)
      vf0[dvf] = *(const bf16x8*)(Vtb +
          (size_t)(dvf * 16 + li) * 4096 + kv0 + g * 8);

    // S^T = K Q^T : st[nf][j] = S^T[kv=nf*16+g*4+j][q=w*16+li]
    f32x4 st[4] = {};
#pragma unroll
    for (int ks = 0; ks < 4; ++ks) {
      bf16x8 kf[4];
#pragma unroll
      for (int nf = 0; nf < 4; ++nf) {
        int r = nf * 16 + li;
        int ch = (ks * 4 + g) ^ (r & 7);
        kf[nf] = *(const bf16x8*)(Kl + r * 128 + ch * 8);
      }
#pragma unroll
      for (int nf = 0; nf < 4; ++nf)
        st[nf] = __builtin_amdgcn_mfma_f32_16x16x32_bf16(
            kf[nf], qf[ks], st[nf], 0, 0, 0);
    }

    // V prefetch, second half (kv 32..63)
    bf16x8 vf1[8];
#pragma unroll
    for (int dvf = 0; dvf < 8; ++dvf)
      vf1[dvf] = *(const bf16x8*)(Vtb +
          (size_t)(dvf * 16 + li) * 4096 + kv0 + 32 + g * 8);

    if (kt >= 2 * qt) {  // diagonal tiles: causal mask (kv > q)
      const int dk = kv0 - qt * 128;  // kv-local -> q-local offset
#pragma unroll
      for (int nf = 0; nf < 4; ++nf)
#pragma unroll
        for (int j = 0; j < 4; ++j)
          if (dk + nf * 16 + g * 4 + j > w * 16 + li) st[nf][j] = -1e30f;
    }

    // P = exp2(S) -> b64 stores at P[li*72 + nf*16 + g*4]
#pragma unroll
    for (int nf = 0; nf < 4; ++nf) {
      union { bf16 h[4]; u32x2 v; } u;
#pragma unroll
      for (int j = 0; j < 4; ++j)
        u.h[j] = __float2bfloat16(exp2f(st[nf][j]));
      *(u32x2*)(P + li * 72 + nf * 16 + g * 4) = u.v;
    }

    // O^T += V^T P^T : o[dvf][j] = O^T[dv=dvf*16+g*4+j][q=w*16+li]
    {
      bf16x8 pa0 = *(const bf16x8*)(P + li * 72 + g * 8);
#pragma unroll
      for (int dvf = 0; dvf < 8; ++dvf)
        o[dvf] = __builtin_amdgcn_mfma_f32_16x16x32_bf16(
            vf0[dvf], pa0, o[dvf], 0, 0, 0);
      lacc = __builtin_amdgcn_mfma_f32_16x16x32_bf16(ones, pa0, lacc, 0, 0, 0);
      bf16x8 pa1 = *(const bf16x8*)(P + li * 72 + 32 + g * 8);
#pragma unroll
      for (int dvf = 0; dvf < 8; ++dvf)
        o[dvf] = __builtin_amdgcn_mfma_f32_16x16x32_bf16(
            vf1[dvf], pa1, o[dvf], 0, 0, 0);
      lacc = __builtin_amdgcn_mfma_f32_16x16x32_bf16(ones, pa1, lacc, 0, 0, 0);
    }
    cur ^= 1;
  }

  // partials: O^T lane layout -> b64 stores; l replicated over rows
  bf16* op = o_part + (size_t)slot * (128 * 128);
  float* lp = l_part + slot * 128;
  if (g == 0) lp[w * 16 + li] = lacc[0];
#pragma unroll
  for (int dvf = 0; dvf < 8; ++dvf) {
    union { bf16 h[4]; u32x2 v; } u;
#pragma unroll
    for (int j = 0; j < 4; ++j) u.h[j] = __float2bfloat16(o[dvf][j]);
    *(u32x2*)(op + (size_t)(w * 16 + li) * 128 + dvf * 16 + g * 4) = u.v;
  }
}

// ---------------------------------------------------------------------------
// 4) combine chunk partials: out[row] = sum_c O_c[row] / sum_c l_c[row]
//    base(qt) = b*144 + (a+1)(2a + r), a = qt>>2, r = qt&3; n = a+1 (<=8).
// ---------------------------------------------------------------------------
__global__ __launch_bounds__(256) void k_comb(const bf16* __restrict__ op,
                                              const float* __restrict__ lp,
                                              float* __restrict__ out) {
  int i = blockIdx.x * 256 + threadIdx.x;  // 4-col group index, < 524288
  int row = i >> 5;
  int col4 = (i & 31) * 4;
  int b = row >> 12;
  int rb = row & 4095;
  int qt = rb >> 7;
  int lr = rb & 127;
  int a = qt >> 2, r = qt & 3;
  int base = b * 144 + (a + 1) * (2 * a + r);
  int n = a + 1;
  float l = 0.0f;
  float acc0 = 0, acc1 = 0, acc2 = 0, acc3 = 0;
  for (int c = 0; c < n; ++c) {
    l += lp[(base + c) * 128 + lr];
    union { bf16 h[4]; u32x2 v; } u;
    u.v = *(const u32x2*)(op + (size_t)(base + c) * 16384 + lr * 128 + col4);
    acc0 += __bfloat162float(u.h[0]);
    acc1 += __bfloat162float(u.h[1]);
    acc2 += __bfloat162float(u.h[2]);
    acc3 += __bfloat162float(u.h[3]);
  }
  float linv = 1.0f / l;
  float4 rv;
  rv.x = acc0 * linv; rv.y = acc1 * linv; rv.z = acc2 * linv; rv.w = acc3 * linv;
  ((float4*)out)[i] = rv;
}

// ---------------------------------------------------------------------------
extern "C" void kernel_launch(void* const* d_in, const int* in_sizes, int n_in,
                              void* d_out, int out_size, void* d_ws, size_t ws_size,
                              hipStream_t stream) {
  const float* X  = (const float*)d_in[0];
  const float* Wq = (const float*)d_in[1];
  const float* bq = (const float*)d_in[2];
  const float* Wk = (const float*)d_in[3];
  const float* bk = (const float*)d_in[4];
  const float* Wv = (const float*)d_in[5];
  const float* bv = (const float*)d_in[6];
  float* out = (float*)d_out;

  char* ws = (char*)d_ws;
  // layout (bytes) — fully disjoint, extent 32,538,624 (proven size)
  bf16* Wt  = (bf16*)(ws + 0);              //    786,432
  bf16* Qb  = (bf16*)(ws + 786432);         //  4,194,304
  bf16* Kb  = (bf16*)(ws + 4980736);        //  4,194,304
  bf16* Vt  = (bf16*)(ws + 9175040);        //  4,194,304
  bf16* o_part = (bf16*)(ws + 13369344);    // 18,874,368 (576*128*128*2)
  float* l_part = (float*)(ws + 32243712);  //    294,912

  k_wt<<<dim3(16, 2, 3), dim3(256), 0, stream>>>(Wq, Wk, Wv, Wt);
  k_qkv<<<dim3(256), dim3(512), 0, stream>>>(X, Wt, bq, bk, bv, Qb, Kb, Vt);
  k_attn<<<dim3(576), dim3(512), 0, stream>>>(Qb, Kb, Vt, o_part, l_part);
  k_comb<<<dim3(2048), dim3(256), 0, stream>>>(o_part, l_part, out);
}

// Round 9
// 89.753 us; speedup vs baseline: 1.6119x; 1.6119x over previous
//
#include <hip/hip_runtime.h>
#include <hip/hip_bf16.h>
#include <stdint.h>

// ============================================================================
// Fused causal self-attention block: QKV projection + flash attention.
// bf16 MFMA. No-max softmax (scores bounded; log2e folded into Q scale).
// k_attn v8.1: ALL operands through LDS (K and V staged via global_load_lds,
// double-buffered, XOR-swizzled; batched ds_read_b128 fragment reads).
// Waves own 32 q-rows (2 B-frags); 4-wave blocks cover 128 q-rows; kv-chunks
// <=8 tiles, 576 blocks, heavy-first, XCD-bijective. P via per-wave LDS,
// kv-halved (stride-36). Swapped QK^T (S^T) + transposed PV (O^T).
// FIX vs v8: partials written at the WORK index (b*144+s), matching k_comb,
// not the heavy-first-reversed block slot.
// ============================================================================

typedef __bf16 bf16x8 __attribute__((ext_vector_type(8)));
typedef float  f32x4  __attribute__((ext_vector_type(4)));
typedef unsigned int u32x4 __attribute__((ext_vector_type(4)));
typedef unsigned int u32x2 __attribute__((ext_vector_type(2)));

using bf16 = __hip_bfloat16;

#define AS1 __attribute__((address_space(1)))
#define AS3 __attribute__((address_space(3)))

__device__ __forceinline__ void gl_lds16(const void* g, void* l) {
  __builtin_amdgcn_global_load_lds((AS1 uint32_t*)g, (AS3 uint32_t*)l, 16, 0, 0);
}

// ---------------------------------------------------------------------------
// 1) W [1024][128] fp32 -> Wt[z][128][1024] bf16 (transpose via LDS tile)
// ---------------------------------------------------------------------------
__global__ __launch_bounds__(256) void k_wt(const float* __restrict__ Wq,
                                            const float* __restrict__ Wk,
                                            const float* __restrict__ Wv,
                                            bf16* __restrict__ Wt) {
  __shared__ bf16 t[64][72];
  const float* W = blockIdx.z == 0 ? Wq : (blockIdx.z == 1 ? Wk : Wv);
  int k0 = blockIdx.x * 64, n0 = blockIdx.y * 64;
  int tid = threadIdx.x;
  int r = tid >> 4, c4 = (tid & 15) * 4;
#pragma unroll
  for (int s = 0; s < 4; ++s) {
    int rr = r + s * 16;
    float4 v = *(const float4*)(W + (size_t)(k0 + rr) * 128 + n0 + c4);
    t[rr][c4 + 0] = __float2bfloat16(v.x);
    t[rr][c4 + 1] = __float2bfloat16(v.y);
    t[rr][c4 + 2] = __float2bfloat16(v.z);
    t[rr][c4 + 3] = __float2bfloat16(v.w);
  }
  __syncthreads();
  bf16* out = Wt + (size_t)blockIdx.z * 128 * 1024;
#pragma unroll
  for (int s = 0; s < 4; ++s) {
    int rn = r + s * 16;
    union { bf16 h[4]; u32x2 v; } u;
    u.h[0] = t[c4 + 0][rn]; u.h[1] = t[c4 + 1][rn];
    u.h[2] = t[c4 + 2][rn]; u.h[3] = t[c4 + 3][rn];
    *(u32x2*)(out + (size_t)(n0 + rn) * 1024 + k0 + c4) = u.v;
  }
}

// ---------------------------------------------------------------------------
// 2) fused QKV projection + in-kernel V transpose (unchanged, proven)
// ---------------------------------------------------------------------------
__global__ __launch_bounds__(512) void k_qkv(const float* __restrict__ X,
                                             const bf16* __restrict__ Wt,
                                             const float* __restrict__ bq,
                                             const float* __restrict__ bk,
                                             const float* __restrict__ bv,
                                             bf16* __restrict__ Qo,
                                             bf16* __restrict__ Ko,
                                             bf16* __restrict__ Vt) {
  __shared__ __align__(16) char smem[65536];
  float* Xs = (float*)smem;                  // [2][64*32] f32, 16 KB
  bf16* Ws = (bf16*)(smem + 16384);          // [2][3*128*32] bf16, 48 KB
  bf16* Vs = (bf16*)smem;                    // epilogue: [64][136], 17.4 KB

  const int m0 = blockIdx.x * 64;
  const int tid = threadIdx.x;
  const int lane = tid & 63;
  const int li = lane & 15, g = lane >> 4;
  const int wid = tid >> 6;
  const int wm = wid >> 2, wn = wid & 3;

  const int xr = tid >> 3;
  const int xc32 = (tid & 7) >> 1;
  const int xhf = tid & 1;
  const int wr = tid >> 2;
  const int wc = tid & 3;

  f32x4 acc[3][2][2] = {};

  {
    gl_lds16(X + (size_t)(m0 + xr) * 1024 + (xc32 ^ (xr & 3)) * 8 + xhf * 4,
             Xs + tid * 4);
#pragma unroll
    for (int z = 0; z < 3; ++z)
      gl_lds16(Wt + (size_t)z * 131072 + (size_t)wr * 1024 + (wc ^ (wr & 3)) * 8,
               Ws + z * 4096 + tid * 8);
  }
  int cur = 0;
  for (int kt = 0; kt < 32; ++kt) {
    __syncthreads();
    if (kt < 31) {
      const int k0 = (kt + 1) * 32;
      gl_lds16(X + (size_t)(m0 + xr) * 1024 + k0 + (xc32 ^ (xr & 3)) * 8 + xhf * 4,
               Xs + (cur ^ 1) * 2048 + tid * 4);
#pragma unroll
      for (int z = 0; z < 3; ++z)
        gl_lds16(Wt + (size_t)z * 131072 + (size_t)wr * 1024 + k0 + (wc ^ (wr & 3)) * 8,
                 Ws + (cur ^ 1) * 12288 + z * 4096 + tid * 8);
    }
    bf16x8 af[2];
#pragma unroll
    for (int mf = 0; mf < 2; ++mf) {
      int r = wm * 32 + mf * 16 + li;
      const float* xp = Xs + cur * 2048 + r * 32 + ((g ^ (r & 3)) * 8);
      f32x4 x0 = *(const f32x4*)xp;
      f32x4 x1 = *(const f32x4*)(xp + 4);
      union { bf16 h[8]; bf16x8 v; } u;
      u.h[0] = __float2bfloat16(x0[0]); u.h[1] = __float2bfloat16(x0[1]);
      u.h[2] = __float2bfloat16(x0[2]); u.h[3] = __float2bfloat16(x0[3]);
      u.h[4] = __float2bfloat16(x1[0]); u.h[5] = __float2bfloat16(x1[1]);
      u.h[6] = __float2bfloat16(x1[2]); u.h[7] = __float2bfloat16(x1[3]);
      af[mf] = u.v;
    }
#pragma unroll
    for (int z = 0; z < 3; ++z) {
#pragma unroll
      for (int nf = 0; nf < 2; ++nf) {
        int r = wn * 32 + nf * 16 + li;
        bf16x8 bfrag =
            *(const bf16x8*)(Ws + cur * 12288 + z * 4096 + r * 32 + ((g ^ (r & 3)) * 8));
#pragma unroll
        for (int mf = 0; mf < 2; ++mf)
          acc[z][mf][nf] = __builtin_amdgcn_mfma_f32_16x16x32_bf16(
              af[mf], bfrag, acc[z][mf][nf], 0, 0, 0);
      }
    }
    cur ^= 1;
  }

#pragma unroll
  for (int z = 0; z < 2; ++z) {
    const float* bias = z == 0 ? bq : bk;
    bf16* Out = z == 0 ? Qo : Ko;
    const float scale = z == 0 ? 0.12752404368678202f : 1.0f;
#pragma unroll
    for (int nf = 0; nf < 2; ++nf) {
      int col = wn * 32 + nf * 16 + li;
      float bb = bias[col];
#pragma unroll
      for (int mf = 0; mf < 2; ++mf)
#pragma unroll
        for (int j = 0; j < 4; ++j) {
          int row = m0 + wm * 32 + mf * 16 + g * 4 + j;
          Out[(size_t)row * 128 + col] =
              __float2bfloat16((acc[z][mf][nf][j] + bb) * scale);
        }
    }
  }

  __syncthreads();
#pragma unroll
  for (int nf = 0; nf < 2; ++nf) {
    int col = wn * 32 + nf * 16 + li;
    float bb = bv[col];
#pragma unroll
    for (int mf = 0; mf < 2; ++mf)
#pragma unroll
      for (int j = 0; j < 4; ++j) {
        int row = wm * 32 + mf * 16 + g * 4 + j;
        Vs[row * 136 + col] = __float2bfloat16(acc[2][mf][nf][j] + bb);
      }
  }
  __syncthreads();
  const int b = m0 >> 12;
  const int s_off = m0 & 4095;
#pragma unroll
  for (int t2 = 0; t2 < 2; ++t2) {
    int idx = tid + 512 * t2;
    int dv = idx & 127;
    int sg = idx >> 7;
    union { bf16 h[8]; u32x4 v; } u;
#pragma unroll
    for (int si = 0; si < 8; ++si) u.h[si] = Vs[(sg * 8 + si) * 136 + dv];
    *(u32x4*)(Vt + (size_t)(b * 128 + dv) * 4096 + s_off + sg * 8) = u.v;
  }
}

// ---------------------------------------------------------------------------
// 3) causal flash attention v8.1. 256 thr = 4 waves x 32 q-rows (q-tile 128).
//    kv tiles = 2(qt+1), chunks <=8, blocks/batch = 144, grid 576.
//    base(qt) = (M+1)(2M + (qt&3)), M = qt>>2; nch = (qt+4)>>2.
//    K,V dbuf LDS (global_load_lds, XOR-swizzled); P per-wave LDS stride-36,
//    kv-halved. LDS 73.4 KB -> 2 blocks/CU. Partials at WORK index b*144+s.
// ---------------------------------------------------------------------------
__global__ __launch_bounds__(256, 2) void k_attn(const bf16* __restrict__ Qb,
                                                 const bf16* __restrict__ Kb,
                                                 const bf16* __restrict__ Vt,
                                                 bf16* __restrict__ o_part,
                                                 float* __restrict__ l_part) {
  __shared__ __align__(16) bf16 Kls[2][64 * 128];  // 32 KB [kv][d] swizzled
  __shared__ __align__(16) bf16 Vls[2][128 * 64];  // 32 KB [dv][kv] swizzled
  __shared__ __align__(16) bf16 Pls[4][32 * 36];   // 9.2 KB per-wave P halves

  const int bid = blockIdx.x;
  const int xcd = bid & 7;
  const int slot = xcd * 72 + (bid >> 3);     // bijective (576 = 8*72)
  const int b = slot / 144;
  const int s = 143 - (slot - b * 144);       // heavy-first work index
  const int widx = b * 144 + s;               // partial-buffer index (k_comb's)
  int qt = 0;
#pragma unroll
  for (int q2 = 1; q2 < 32; ++q2) {
    int M = q2 >> 2;
    if ((M + 1) * (2 * M + (q2 & 3)) <= s) qt = q2;
  }
  const int Mq = qt >> 2;
  const int chunk = s - (Mq + 1) * (2 * Mq + (qt & 3));
  const int ntiles = 2 * qt + 2;
  const int nch = (qt + 4) >> 2;
  const int clen = ntiles / nch;
  const int crem = ntiles - clen * nch;
  const int kt0 = chunk * clen + min(chunk, crem);
  const int kt1 = kt0 + clen + (chunk < crem ? 1 : 0) - 1;

  const int tid = threadIdx.x;
  const int lane = tid & 63;
  const int li = lane & 15, g = lane >> 4;
  const int w = tid >> 6;

  // Q fragments: 32 q-rows/wave via 2 B-frags (q = qt*128 + w*32 + qb*16 + li)
  bf16x8 qf[2][4];
#pragma unroll
  for (int qb = 0; qb < 2; ++qb)
#pragma unroll
    for (int ks = 0; ks < 4; ++ks)
      qf[qb][ks] = *(const bf16x8*)(Qb +
          (size_t)(b * 4096 + qt * 128 + w * 32 + qb * 16 + li) * 128 +
          ks * 32 + g * 8);

  f32x4 o[2][8] = {};
  f32x4 lacc[2] = {};
  bf16x8 ones;
#pragma unroll
  for (int e = 0; e < 8; ++e) ones[e] = (__bf16)1.0f;

  bf16* P = &Pls[w][0];
  const bf16* Vtb = Vt + (size_t)b * 128 * 4096;

  // prologue: stage K+V tile kt0 -> buf 0 (8 gl_lds16/thread)
  {
    const int kv0 = kt0 * 64;
#pragma unroll
    for (int ii = 0; ii < 4; ++ii) {
      int c = tid + 256 * ii;
      int r = c >> 4, cc = c & 15;
      gl_lds16(Kb + (size_t)(b * 4096 + kv0 + r) * 128 + (cc ^ (r & 7)) * 8,
               &Kls[0][c * 8]);
      int r2 = c >> 3, cc2 = c & 7;
      gl_lds16(Vtb + (size_t)r2 * 4096 + kv0 + (cc2 ^ (r2 & 7)) * 8,
               &Vls[0][c * 8]);
    }
  }
  int cur = 0;
  for (int kt = kt0; kt <= kt1; ++kt) {
    __syncthreads();  // buf[cur] staged; all waves done with buf[cur^1]
    if (kt < kt1) {
      const int kv0n = (kt + 1) * 64;
#pragma unroll
      for (int ii = 0; ii < 4; ++ii) {
        int c = tid + 256 * ii;
        int r = c >> 4, cc = c & 15;
        gl_lds16(Kb + (size_t)(b * 4096 + kv0n + r) * 128 + (cc ^ (r & 7)) * 8,
                 &Kls[cur ^ 1][c * 8]);
        int r2 = c >> 3, cc2 = c & 7;
        gl_lds16(Vtb + (size_t)r2 * 4096 + kv0n + (cc2 ^ (r2 & 7)) * 8,
                 &Vls[cur ^ 1][c * 8]);
      }
    }
    const bf16* Kl = &Kls[cur][0];
    const bf16* Vl = &Vls[cur][0];
    const int kv0 = kt * 64;

    // S^T = K Q^T : st[qb][nf][j] = S^T[kv=nf*16+g*4+j][q=w*32+qb*16+li]
    f32x4 st[2][4] = {};
#pragma unroll
    for (int ks = 0; ks < 4; ++ks) {
      bf16x8 kf[4];
#pragma unroll
      for (int nf = 0; nf < 4; ++nf) {
        int r = nf * 16 + li;
        int ch = (ks * 4 + g) ^ (r & 7);
        kf[nf] = *(const bf16x8*)(Kl + r * 128 + ch * 8);
      }
#pragma unroll
      for (int nf = 0; nf < 4; ++nf)
#pragma unroll
        for (int qb = 0; qb < 2; ++qb)
          st[qb][nf] = __builtin_amdgcn_mfma_f32_16x16x32_bf16(
              kf[nf], qf[qb][ks], st[qb][nf], 0, 0, 0);
    }

    if (kt >= 2 * qt) {  // diagonal tiles: causal mask (kv > q)
      const int dk = kv0 - qt * 128;
#pragma unroll
      for (int qb = 0; qb < 2; ++qb) {
        const int qloc = w * 32 + qb * 16 + li;
#pragma unroll
        for (int nf = 0; nf < 4; ++nf)
#pragma unroll
          for (int j = 0; j < 4; ++j)
            if (dk + nf * 16 + g * 4 + j > qloc) st[qb][nf][j] = -1e30f;
      }
    }

    // kv-halved softmax+PV: half h covers kv [h*32, h*32+32)
#pragma unroll
    for (int h = 0; h < 2; ++h) {
      // P = exp2(S) -> b64 stores, P[q'=qb*16+li][c = nfh*16+g*4], stride 36
#pragma unroll
      for (int qb = 0; qb < 2; ++qb)
#pragma unroll
        for (int nfh = 0; nfh < 2; ++nfh) {
          const f32x4 sv = st[qb][h * 2 + nfh];
          union { bf16 h4[4]; u32x2 v; } u;
#pragma unroll
          for (int j = 0; j < 4; ++j)
            u.h4[j] = __float2bfloat16(exp2f(sv[j]));
          *(u32x2*)(P + (qb * 16 + li) * 36 + nfh * 16 + g * 4) = u.v;
        }
      // pa: B-frag P^T[k=kv half][n=q], b128 read
      bf16x8 pa[2];
#pragma unroll
      for (int qb = 0; qb < 2; ++qb)
        pa[qb] = *(const bf16x8*)(P + (qb * 16 + li) * 36 + g * 8);
      // O^T += V^T P^T ; l via ones-MFMA
#pragma unroll
      for (int dvf = 0; dvf < 8; ++dvf) {
        int r = dvf * 16 + li;
        int ch = (h * 4 + g) ^ (li & 7);
        bf16x8 vf = *(const bf16x8*)(Vl + r * 64 + ch * 8);
#pragma unroll
        for (int qb = 0; qb < 2; ++qb)
          o[qb][dvf] = __builtin_amdgcn_mfma_f32_16x16x32_bf16(
              vf, pa[qb], o[qb][dvf], 0, 0, 0);
      }
#pragma unroll
      for (int qb = 0; qb < 2; ++qb)
        lacc[qb] = __builtin_amdgcn_mfma_f32_16x16x32_bf16(
            ones, pa[qb], lacc[qb], 0, 0, 0);
    }
    cur ^= 1;
  }

  // partials at WORK index widx: O^T lane layout -> b64 stores
  bf16* op = o_part + (size_t)widx * (128 * 128);
  float* lp = l_part + widx * 128;
#pragma unroll
  for (int qb = 0; qb < 2; ++qb) {
    const int qloc = w * 32 + qb * 16 + li;
    if (g == 0) lp[qloc] = lacc[qb][0];
#pragma unroll
    for (int dvf = 0; dvf < 8; ++dvf) {
      union { bf16 h4[4]; u32x2 v; } u;
#pragma unroll
      for (int j = 0; j < 4; ++j) u.h4[j] = __float2bfloat16(o[qb][dvf][j]);
      *(u32x2*)(op + (size_t)qloc * 128 + dvf * 16 + g * 4) = u.v;
    }
  }
}

// ---------------------------------------------------------------------------
// 4) combine chunk partials: out[row] = sum_c O_c[row] / sum_c l_c[row]
//    q-tile 128: qt = rb>>7; base(qt) = (M+1)(2M + (qt&3)), M=qt>>2;
//    n = (qt+4)>>2 (<=8). partial strides: O 16384, l 128.
// ---------------------------------------------------------------------------
__global__ __launch_bounds__(256) void k_comb(const bf16* __restrict__ op,
                                              const float* __restrict__ lp,
                                              float* __restrict__ out) {
  int i = blockIdx.x * 256 + threadIdx.x;  // 4-col group index, < 524288
  int row = i >> 5;
  int col4 = (i & 31) * 4;
  int b = row >> 12;
  int rb = row & 4095;
  int qt = rb >> 7;
  int lr = rb & 127;
  int M = qt >> 2;
  int base = b * 144 + (M + 1) * (2 * M + (qt & 3));
  int n = (qt + 4) >> 2;
  float l = 0.0f;
  float acc0 = 0, acc1 = 0, acc2 = 0, acc3 = 0;
  for (int c = 0; c < n; ++c) {
    l += lp[(base + c) * 128 + lr];
    union { bf16 h[4]; u32x2 v; } u;
    u.v = *(const u32x2*)(op + (size_t)(base + c) * 16384 + lr * 128 + col4);
    acc0 += __bfloat162float(u.h[0]);
    acc1 += __bfloat162float(u.h[1]);
    acc2 += __bfloat162float(u.h[2]);
    acc3 += __bfloat162float(u.h[3]);
  }
  float linv = 1.0f / l;
  float4 rv;
  rv.x = acc0 * linv; rv.y = acc1 * linv; rv.z = acc2 * linv; rv.w = acc3 * linv;
  ((float4*)out)[i] = rv;
}

// ---------------------------------------------------------------------------
extern "C" void kernel_launch(void* const* d_in, const int* in_sizes, int n_in,
                              void* d_out, int out_size, void* d_ws, size_t ws_size,
                              hipStream_t stream) {
  const float* X  = (const float*)d_in[0];
  const float* Wq = (const float*)d_in[1];
  const float* bq = (const float*)d_in[2];
  const float* Wk = (const float*)d_in[3];
  const float* bk = (const float*)d_in[4];
  const float* Wv = (const float*)d_in[5];
  const float* bv = (const float*)d_in[6];
  float* out = (float*)d_out;

  char* ws = (char*)d_ws;
  // layout (bytes) — fully disjoint, extent 32,538,624 (proven size)
  bf16* Wt  = (bf16*)(ws + 0);              //    786,432
  bf16* Qb  = (bf16*)(ws + 786432);         //  4,194,304
  bf16* Kb  = (bf16*)(ws + 4980736);        //  4,194,304
  bf16* Vt  = (bf16*)(ws + 9175040);        //  4,194,304
  bf16* o_part = (bf16*)(ws + 13369344);    // 18,874,368 (576*128*128*2)
  float* l_part = (float*)(ws + 32243712);  //    294,912

  k_wt<<<dim3(16, 2, 3), dim3(256), 0, stream>>>(Wq, Wk, Wv, Wt);
  k_qkv<<<dim3(256), dim3(512), 0, stream>>>(X, Wt, bq, bk, bv, Qb, Kb, Vt);
  k_attn<<<dim3(576), dim3(256), 0, stream>>>(Qb, Kb, Vt, o_part, l_part);
  k_comb<<<dim3(2048), dim3(256), 0, stream>>>(o_part, l_part, out);
}